// Round 6
// baseline (168.765 us; speedup 1.0000x reference)
//
#include <hip/hip_runtime.h>

// Problem constants (from reference)
constexpr int B_  = 2;
constexpr int T_  = 1024;
constexpr int NQ  = 32;
constexpr int NKV = 8;
constexpr int D_  = 128;

constexpr int BM = 64;            // query rows per workgroup (4 waves x 16)
constexpr int BN = 64;            // keys per KV iteration
constexpr int NTILE = T_ / BM;    // 16 q-tiles, also 16 kv-blocks of 64
constexpr float MASK_NEG = -3.0e38f;

typedef _Float16 f16;
typedef f16 f16x4 __attribute__((ext_vector_type(4)));
typedef f16 f16x8 __attribute__((ext_vector_type(8)));
typedef float floatx4 __attribute__((ext_vector_type(4)));

// Pre-converted K (fp16, [b][kv][s][d]) and pre-transposed V
// (fp16, tile-major [b][kv][blk][d][64]).
// STATIC device globals, not d_ws: R5 wrote 8 MB into d_ws without checking
// ws_size -- OOB scratch writes corrupted harness state (pass-once,
// fail-post-timing signature). Static allocation removes that failure mode;
// prep fully rewrites both arrays every call (no cross-call state).
__device__ __align__(16) f16 g_K16 [(size_t)B_ * NKV * T_ * D_];   // 4 MB
__device__ __align__(16) f16 g_Vt16[(size_t)B_ * NKV * T_ * D_];   // 4 MB

// ---------------------------------------------------------------------------
// Prep kernel: convert + relayout K and V. Moves all fp32->fp16 conversion
// and the V transpose out of the attention hot loop.
__global__ __launch_bounds__(256)
void prep_kernel(const float* __restrict__ K, const float* __restrict__ V) {
    __shared__ f16 lv[64][136];
    const int sblk = blockIdx.x;   // 0..15
    const int kv   = blockIdx.y;   // 0..7
    const int b    = blockIdx.z;   // 0..1
    const int tid  = threadIdx.x;
    const int s0   = sblk * 64;
    const size_t inbase = ((size_t)b * T_) * NKV * D_ + (size_t)kv * D_;

    // K: straight convert, coalesced in and out
    f16* kout = g_K16 + ((size_t)(b * NKV + kv) * T_ + s0) * D_;
#pragma unroll
    for (int p = 0; p < 8; ++p) {
        const int u = tid + 256 * p;          // 2048 float4 units
        const int s = u >> 5, d4 = u & 31;
        float4 f = *(const float4*)(K + inbase + (size_t)(s0 + s) * NKV * D_ + d4 * 4);
        f16x4 hh; hh[0] = (f16)f.x; hh[1] = (f16)f.y; hh[2] = (f16)f.z; hh[3] = (f16)f.w;
        *(f16x4*)(kout + s * D_ + d4 * 4) = hh;
    }
    // V: convert into LDS, write out transposed [d][s_loc]
#pragma unroll
    for (int p = 0; p < 8; ++p) {
        const int u = tid + 256 * p;
        const int s = u >> 5, d4 = u & 31;
        float4 f = *(const float4*)(V + inbase + (size_t)(s0 + s) * NKV * D_ + d4 * 4);
        f16x4 hh; hh[0] = (f16)f.x; hh[1] = (f16)f.y; hh[2] = (f16)f.z; hh[3] = (f16)f.w;
        *(f16x4*)&lv[s][d4 * 4] = hh;
    }
    __syncthreads();
    f16* vout = g_Vt16 + (size_t)((b * NKV + kv) * 16 + sblk) * 128 * 64;
#pragma unroll
    for (int p = 0; p < 4; ++p) {
        const int u = tid + 256 * p;          // 1024 8-f16 units
        const int d = u >> 3, cu = u & 7;
        f16x8 hh;
#pragma unroll
        for (int j = 0; j < 8; ++j) hh[j] = lv[cu * 8 + j][d];
        *(f16x8*)(vout + d * 64 + cu * 8) = hh;
    }
}

// ---------------------------------------------------------------------------
// Main flash-attention kernel. Single barrier per KV iteration, LDS
// double-buffered; staging = dwordx4 global loads + b128 LDS writes (fp16
// pre-converted); l_i via ones-column MFMA (no sum-shfl chain).
__global__ __launch_bounds__(256, 2)
void fa_kernel(const float* __restrict__ Qg, const int* __restrict__ seg,
               float* __restrict__ Og) {
    __shared__ f16 lds_k[2][BN][136];    // 2 x 17408 B
    __shared__ f16 lds_vt[2][D_][72];    // 2 x 18432 B
    __shared__ f16 lds_p[4][16][72];     // 9216 B   (total 79.0 KB -> 2 blocks/CU)

    const int pair = blockIdx.x;        // 0..7
    const int h    = blockIdx.y;        // 0..31
    const int b    = blockIdx.z;        // 0..1
    const int kv   = h >> 2;

    const int tid  = threadIdx.x;
    const int wave = tid >> 6;
    const int lane = tid & 63;
    const int quad = lane >> 4;
    const int ln   = lane & 15;

    const int* segb = seg + b * T_;
    const f16* kbase = g_K16 + (size_t)(b * NKV + kv) * T_ * D_;
    const f16* vbase = g_Vt16 + (size_t)(b * NKV + kv) * 16 * 128 * 64;

    f16x8 vones;
#pragma unroll
    for (int j = 0; j < 8; ++j) vones[j] = (f16)1.0f;

    for (int sub = 0; sub < 2; ++sub) {
        const int tile = sub ? pair : (NTILE - 1 - pair);  // heavy tile first
        const int t0 = tile * BM;

        // ---- Q fragments (A-layout: m = ln, k = quad*8+j)
        const int qrow = t0 + wave * 16 + ln;
        const float* qptr = Qg + (((size_t)b * T_ + qrow) * NQ + h) * D_;
        f16x8 qfrag[4];
#pragma unroll
        for (int c = 0; c < 4; ++c) {
            const float* p = qptr + c * 32 + quad * 8;
            float4 f0 = *(const float4*)(p);
            float4 f1 = *(const float4*)(p + 4);
            f16x8 v;
            v[0] = (f16)f0.x; v[1] = (f16)f0.y; v[2] = (f16)f0.z; v[3] = (f16)f0.w;
            v[4] = (f16)f1.x; v[5] = (f16)f1.y; v[6] = (f16)f1.z; v[7] = (f16)f1.w;
            qfrag[c] = v;
        }

        int trow[4], segq[4];
#pragma unroll
        for (int r = 0; r < 4; ++r) {
            trow[r] = t0 + wave * 16 + quad * 4 + r;
            segq[r] = segb[trow[r]];
        }
        const int seg_lo = segb[t0];

        // first active KV block (sorted ids): ballot over dead 16-chunks
        unsigned long long bal = __ballot(segb[lane * 16 + 15] < seg_lo);
        const int blk_start = __popcll(bal) >> 2;
        const int nblk = tile + 1;      // causal limit

        float  m_i[4];
        floatx4 o_acc[9];               // [8] = running row-sum (ones column)
#pragma unroll
        for (int r = 0; r < 4; ++r) m_i[r] = -1.0e30f;
#pragma unroll
        for (int dt = 0; dt < 9; ++dt) o_acc[dt] = floatx4{0.f, 0.f, 0.f, 0.f};

        // ---- prologue: stage first block into buf 0
        uint4 kst[4], vst[4];
        {
            const f16* kp = kbase + (size_t)blk_start * BN * D_;
            const f16* vp = vbase + (size_t)blk_start * 128 * 64;
#pragma unroll
            for (int p = 0; p < 4; ++p) kst[p] = *(const uint4*)(kp + (tid + 256 * p) * 8);
#pragma unroll
            for (int p = 0; p < 4; ++p) vst[p] = *(const uint4*)(vp + (tid + 256 * p) * 8);
        }
        __syncthreads();   // previous sub-tile's readers are done with LDS
#pragma unroll
        for (int p = 0; p < 4; ++p) {
            const int u = tid + 256 * p;
            *(uint4*)&lds_k[0][u >> 4][(u & 15) * 8] = kst[p];
        }
#pragma unroll
        for (int p = 0; p < 4; ++p) {
            const int u = tid + 256 * p;
            *(uint4*)&lds_vt[0][u >> 3][(u & 7) * 8] = vst[p];
        }

        int buf = 0;
        for (int blk = blk_start; blk < nblk; ++blk) {
            const int s0 = blk * BN;
            __syncthreads();   // [only barrier] buf tiles visible; prev reads done

            // ---- issue next block's global loads immediately (land during compute)
            const bool more = (blk + 1 < nblk);
            if (more) {
                const f16* kp = kbase + (size_t)(blk + 1) * BN * D_;
                const f16* vp = vbase + (size_t)(blk + 1) * 128 * 64;
#pragma unroll
                for (int p = 0; p < 4; ++p) kst[p] = *(const uint4*)(kp + (tid + 256 * p) * 8);
#pragma unroll
                for (int p = 0; p < 4; ++p) vst[p] = *(const uint4*)(vp + (tid + 256 * p) * 8);
            }
            int segs[4];
#pragma unroll
            for (int nt = 0; nt < 4; ++nt) segs[nt] = segb[s0 + nt * 16 + ln];

            // ---- S = Q K^T
            floatx4 sc[4];
#pragma unroll
            for (int nt = 0; nt < 4; ++nt) {
                floatx4 acc = floatx4{0.f, 0.f, 0.f, 0.f};
#pragma unroll
                for (int c = 0; c < 4; ++c) {
                    f16x8 kf = *(const f16x8*)&lds_k[buf][nt * 16 + ln][c * 32 + quad * 8];
                    acc = __builtin_amdgcn_mfma_f32_16x16x32_f16(qfrag[c], kf, acc, 0, 0, 0);
                }
                sc[nt] = acc;
            }

            // ---- mask (causal AND segment); C-layout: col=ln, row=quad*4+r
#pragma unroll
            for (int nt = 0; nt < 4; ++nt) {
                const int s = s0 + nt * 16 + ln;
#pragma unroll
                for (int r = 0; r < 4; ++r) {
                    const bool ok = (s <= trow[r]) && (segs[nt] == segq[r]);
                    sc[nt][r] = ok ? sc[nt][r] : MASK_NEG;
                }
            }

            // ---- online softmax: max via shfl chain; sum via ones-MFMA later
            floatx4 av;
#pragma unroll
            for (int r = 0; r < 4; ++r) {
                float mx = fmaxf(fmaxf(sc[0][r], sc[1][r]), fmaxf(sc[2][r], sc[3][r]));
                mx = fmaxf(mx, __shfl_xor(mx, 1));
                mx = fmaxf(mx, __shfl_xor(mx, 2));
                mx = fmaxf(mx, __shfl_xor(mx, 4));
                mx = fmaxf(mx, __shfl_xor(mx, 8));
                const float mnew = fmaxf(m_i[r], mx);
                av[r] = __expf(m_i[r] - mnew);
                m_i[r] = mnew;
                sc[0][r] = __expf(sc[0][r] - mnew);
                sc[1][r] = __expf(sc[1][r] - mnew);
                sc[2][r] = __expf(sc[2][r] - mnew);
                sc[3][r] = __expf(sc[3][r] - mnew);
            }
#pragma unroll
            for (int dt = 0; dt < 9; ++dt) o_acc[dt] *= av;

            // ---- P: C-layout -> per-wave LDS -> A-layout frags
#pragma unroll
            for (int nt = 0; nt < 4; ++nt)
#pragma unroll
                for (int r = 0; r < 4; ++r)
                    lds_p[wave][quad * 4 + r][nt * 16 + ln] = (f16)sc[nt][r];

            __builtin_amdgcn_s_waitcnt(0xc07f);   // lgkmcnt(0) only

            f16x8 af0 = *(const f16x8*)&lds_p[wave][ln][quad * 8];
            f16x8 af1 = *(const f16x8*)&lds_p[wave][ln][32 + quad * 8];

            // ---- write staged next block into the other buffer
            if (more) {
                const int ob = buf ^ 1;
#pragma unroll
                for (int p = 0; p < 4; ++p) {
                    const int u = tid + 256 * p;
                    *(uint4*)&lds_k[ob][u >> 4][(u & 15) * 8] = kst[p];
                }
#pragma unroll
                for (int p = 0; p < 4; ++p) {
                    const int u = tid + 256 * p;
                    *(uint4*)&lds_vt[ob][u >> 3][(u & 7) * 8] = vst[p];
                }
            }

            // ---- O += P V  (+ ones column accumulates l)
#pragma unroll
            for (int dt = 0; dt < 8; ++dt) {
                f16x8 b0 = *(const f16x8*)&lds_vt[buf][dt * 16 + ln][quad * 8];
                f16x8 b1 = *(const f16x8*)&lds_vt[buf][dt * 16 + ln][32 + quad * 8];
                o_acc[dt] = __builtin_amdgcn_mfma_f32_16x16x32_f16(af0, b0, o_acc[dt], 0, 0, 0);
                o_acc[dt] = __builtin_amdgcn_mfma_f32_16x16x32_f16(af1, b1, o_acc[dt], 0, 0, 0);
            }
            o_acc[8] = __builtin_amdgcn_mfma_f32_16x16x32_f16(af0, vones, o_acc[8], 0, 0, 0);
            o_acc[8] = __builtin_amdgcn_mfma_f32_16x16x32_f16(af1, vones, o_acc[8], 0, 0, 0);

            buf ^= 1;
        }

        // ---- epilogue: normalize + store (fp32, C-layout scatter)
#pragma unroll
        for (int r = 0; r < 4; ++r) {
            const float inv = 1.0f / o_acc[8][r];
            float* optr = Og + (((size_t)b * T_ + trow[r]) * NQ + h) * D_ + ln;
#pragma unroll
            for (int dt = 0; dt < 8; ++dt)
                optr[dt * 16] = o_acc[dt][r] * inv;
        }
    }
}

extern "C" void kernel_launch(void* const* d_in, const int* in_sizes, int n_in,
                              void* d_out, int out_size, void* d_ws, size_t ws_size,
                              hipStream_t stream) {
    const float* Q   = (const float*)d_in[0];
    const float* K   = (const float*)d_in[1];
    const float* V   = (const float*)d_in[2];
    const int*   seg = (const int*)d_in[3];
    float* out = (float*)d_out;

    dim3 pgrid(NTILE, NKV, B_);
    prep_kernel<<<pgrid, 256, 0, stream>>>(K, V);

    dim3 grid(NTILE / 2, NQ, B_);
    fa_kernel<<<grid, 256, 0, stream>>>(Q, seg, out);
}

// Round 7
// 126.033 us; speedup vs baseline: 1.3391x; 1.3391x over previous
//
#include <hip/hip_runtime.h>

// Problem constants (from reference)
constexpr int B_  = 2;
constexpr int T_  = 1024;
constexpr int NQ  = 32;
constexpr int NKV = 8;
constexpr int D_  = 128;

constexpr int BM = 64;            // query rows per workgroup (4 waves x 16)
constexpr int BN = 64;            // keys per KV iteration
constexpr int NTILE = T_ / BM;    // 16 q-tiles = 16 kv-blocks of 64
constexpr float MASK_NEG = -3.0e38f;

typedef _Float16 f16;
typedef f16 f16x4 __attribute__((ext_vector_type(4)));
typedef f16 f16x8 __attribute__((ext_vector_type(8)));
typedef float floatx4 __attribute__((ext_vector_type(4)));

// Static device scratch (NOT d_ws: R5 showed OOB-ws corruption; prep fully
// rewrites both arrays every call). Layouts are XOR-swizzled so the fa
// kernel can DMA them into UNPADDED LDS via global_load_lds (lane-ordered
// contiguous -> padding impossible) and still read conflict-free:
//   K16 [b][kv][s][ch^ (s&7)]  (16 chunks of 8 f16 per 128-d row)
//   Vt16 [b][kv][blk][d][ch ^ (d&7)] (transposed; 8 chunks of 8 f16 per 64-s row)
__device__ __align__(16) f16 g_K16 [(size_t)B_ * NKV * T_ * D_];   // 4 MB
__device__ __align__(16) f16 g_Vt16[(size_t)B_ * NKV * T_ * D_];   // 4 MB

__device__ __forceinline__ void dma16(const f16* g, const f16* l) {
    // async global->LDS, 16 B/lane, lands at lds_base + lane*16
    __builtin_amdgcn_global_load_lds(
        (const __attribute__((address_space(1))) void*)g,
        (__attribute__((address_space(3))) void*)l, 16, 0, 0);
}

// ---------------------------------------------------------------------------
// Prep: fp32 K/V -> fp16, relayout + XOR-swizzle (conversion, transpose and
// swizzle all hoisted out of the attention hot loop).
__global__ __launch_bounds__(256)
void prep_kernel(const float* __restrict__ K, const float* __restrict__ V) {
    __shared__ f16 lv[64][136];
    const int sblk = blockIdx.x;   // 0..15
    const int kv   = blockIdx.y;   // 0..7
    const int b    = blockIdx.z;   // 0..1
    const int tid  = threadIdx.x;
    const int s0   = sblk * 64;
    const size_t inbase = ((size_t)b * T_) * NKV * D_ + (size_t)kv * D_;

    // K: convert + swizzle chunks within each row
    f16* kout = g_K16 + ((size_t)(b * NKV + kv) * T_ + s0) * D_;
#pragma unroll
    for (int p = 0; p < 4; ++p) {
        const int u = tid + 256 * p;          // 1024 chunk units (16 B each)
        const int s = u >> 4, ch = u & 15;
        const float* src = K + inbase + (size_t)(s0 + s) * NKV * D_ + ch * 8;
        float4 f0 = *(const float4*)src;
        float4 f1 = *(const float4*)(src + 4);
        f16x8 hh;
        hh[0] = (f16)f0.x; hh[1] = (f16)f0.y; hh[2] = (f16)f0.z; hh[3] = (f16)f0.w;
        hh[4] = (f16)f1.x; hh[5] = (f16)f1.y; hh[6] = (f16)f1.z; hh[7] = (f16)f1.w;
        *(f16x8*)(kout + s * D_ + ((ch ^ (s & 7)) * 8)) = hh;
    }
    // V: convert into LDS, emit transposed [d][s_loc] with chunk swizzle
#pragma unroll
    for (int p = 0; p < 8; ++p) {
        const int u = tid + 256 * p;
        const int s = u >> 5, d4 = u & 31;
        float4 f = *(const float4*)(V + inbase + (size_t)(s0 + s) * NKV * D_ + d4 * 4);
        f16x4 hh; hh[0] = (f16)f.x; hh[1] = (f16)f.y; hh[2] = (f16)f.z; hh[3] = (f16)f.w;
        *(f16x4*)&lv[s][d4 * 4] = hh;
    }
    __syncthreads();
    f16* vout = g_Vt16 + (size_t)((b * NKV + kv) * 16 + sblk) * 8192;
#pragma unroll
    for (int p = 0; p < 4; ++p) {
        const int u = tid + 256 * p;          // 1024 8-f16 units
        const int d = u >> 3, cu = u & 7;
        f16x8 hh;
#pragma unroll
        for (int j = 0; j < 8; ++j) hh[j] = lv[cu * 8 + j][d];
        *(f16x8*)(vout + d * 64 + ((cu ^ (d & 7)) * 8)) = hh;
    }
}

// ---------------------------------------------------------------------------
// Body macro: one KV block. Separate RK/RV vs WK/WV buffer objects so the
// compiler can prove the DMA into W* doesn't alias ds_reads of R* (no
// spurious vmcnt waits). The loop-top __syncthreads' implicit vmcnt(0)
// drain IS the completion wait for the DMA issued last iteration.
#define FA_BODY(RK, RV, WK, WV, blkv)                                          \
    {                                                                          \
        const int s0 = (blkv) * BN;                                            \
        __syncthreads();                                                       \
        if ((blkv) + 1 < nblk) {                                               \
            const f16* kt = kbase + (size_t)((blkv) + 1) * 8192 + glane;       \
            const f16* vt = vbase + (size_t)((blkv) + 1) * 8192 + glane;       \
            _Pragma("unroll")                                                  \
            for (int i = 0; i < 4; ++i) {                                      \
                dma16(kt + i * 512, WK + wbase + i * 512);                     \
                dma16(vt + i * 512, WV + wbase + i * 512);                     \
            }                                                                  \
        }                                                                      \
        floatx4 sc[4];                                                         \
        _Pragma("unroll")                                                      \
        for (int nt = 0; nt < 4; ++nt) {                                       \
            floatx4 acc = floatx4{0.f, 0.f, 0.f, 0.f};                         \
            _Pragma("unroll")                                                  \
            for (int c = 0; c < 4; ++c) {                                      \
                f16x8 kf = *(const f16x8*)(RK + (nt * 16 + ln) * 128 + kpc[c]);\
                acc = __builtin_amdgcn_mfma_f32_16x16x32_f16(qfrag[c], kf, acc, 0, 0, 0); \
            }                                                                  \
            sc[nt] = acc;                                                      \
        }                                                                      \
        _Pragma("unroll")                                                      \
        for (int nt = 0; nt < 4; ++nt) {                                       \
            const int s = s0 + nt * 16 + ln;                                   \
            const int sgs = lds_seg[s];                                        \
            _Pragma("unroll")                                                  \
            for (int r = 0; r < 4; ++r) {                                      \
                const bool ok = (s <= trow[r]) && (sgs == segq[r]);            \
                sc[nt][r] = ok ? sc[nt][r] : MASK_NEG;                         \
            }                                                                  \
        }                                                                      \
        floatx4 av;                                                            \
        _Pragma("unroll")                                                      \
        for (int r = 0; r < 4; ++r) {                                          \
            float mx = fmaxf(fmaxf(sc[0][r], sc[1][r]), fmaxf(sc[2][r], sc[3][r])); \
            mx = fmaxf(mx, __shfl_xor(mx, 1));                                 \
            mx = fmaxf(mx, __shfl_xor(mx, 2));                                 \
            mx = fmaxf(mx, __shfl_xor(mx, 4));                                 \
            mx = fmaxf(mx, __shfl_xor(mx, 8));                                 \
            const float mnew = fmaxf(m_i[r], mx);                              \
            av[r] = __expf(m_i[r] - mnew);                                     \
            m_i[r] = mnew;                                                     \
            sc[0][r] = __expf(sc[0][r] - mnew);                                \
            sc[1][r] = __expf(sc[1][r] - mnew);                                \
            sc[2][r] = __expf(sc[2][r] - mnew);                                \
            sc[3][r] = __expf(sc[3][r] - mnew);                                \
        }                                                                      \
        _Pragma("unroll")                                                      \
        for (int dt = 0; dt < 9; ++dt) o_acc[dt] *= av;                        \
        _Pragma("unroll")                                                      \
        for (int nt = 0; nt < 4; ++nt)                                         \
            _Pragma("unroll")                                                  \
            for (int r = 0; r < 4; ++r)                                        \
                lds_p[wave][quad * 4 + r][nt * 16 + ln] = (f16)sc[nt][r];      \
        __builtin_amdgcn_s_waitcnt(0xc07f); /* lgkmcnt(0) only */              \
        f16x8 af0 = *(const f16x8*)&lds_p[wave][ln][quad * 8];                 \
        f16x8 af1 = *(const f16x8*)&lds_p[wave][ln][32 + quad * 8];            \
        _Pragma("unroll")                                                      \
        for (int dt = 0; dt < 8; ++dt) {                                       \
            const f16* vr = RV + (dt * 16 + ln) * 64;                          \
            f16x8 b0 = *(const f16x8*)(vr + pc0);                              \
            f16x8 b1 = *(const f16x8*)(vr + pc1);                              \
            o_acc[dt] = __builtin_amdgcn_mfma_f32_16x16x32_f16(af0, b0, o_acc[dt], 0, 0, 0); \
            o_acc[dt] = __builtin_amdgcn_mfma_f32_16x16x32_f16(af1, b1, o_acc[dt], 0, 0, 0); \
        }                                                                      \
        o_acc[8] = __builtin_amdgcn_mfma_f32_16x16x32_f16(af0, vones, o_acc[8], 0, 0, 0); \
        o_acc[8] = __builtin_amdgcn_mfma_f32_16x16x32_f16(af1, vones, o_acc[8], 0, 0, 0); \
    }

__global__ __launch_bounds__(256, 2)
void fa_kernel(const float* __restrict__ Qg, const int* __restrict__ seg,
               float* __restrict__ Og) {
    __shared__ __align__(16) f16 kb0[64 * 128];   // 16 KB each, unpadded
    __shared__ __align__(16) f16 kb1[64 * 128];
    __shared__ __align__(16) f16 vb0[128 * 64];
    __shared__ __align__(16) f16 vb1[128 * 64];
    __shared__ f16 lds_p[4][16][72];              // 9216 B
    __shared__ int lds_seg[T_];                   // 4096 B  (total 78.8 KB)

    const int pair = blockIdx.x;        // 0..7
    const int h    = blockIdx.y;        // 0..31
    const int b    = blockIdx.z;        // 0..1
    const int kv   = h >> 2;

    const int tid  = threadIdx.x;
    const int wave = tid >> 6;
    const int lane = tid & 63;
    const int quad = lane >> 4;
    const int ln   = lane & 15;
    const int sw   = ln & 7;

    // deswizzle constants (per-lane loop invariants), in f16 units
    int kpc[4];
#pragma unroll
    for (int c = 0; c < 4; ++c) kpc[c] = ((4 * c + quad) ^ sw) * 8;
    const int pc0 = (quad ^ sw) * 8;
    const int pc1 = ((quad + 4) ^ sw) * 8;

    // DMA offsets: wave w stages rows [16w,16w+16) of each tile
    const int glane = wave * 2048 + lane * 8;   // per-lane global (f16 units)
    const int wbase = wave * 2048;              // uniform LDS base (f16 units)

    const f16* kbase = g_K16 + (size_t)(b * NKV + kv) * T_ * D_;
    const f16* vbase = g_Vt16 + (size_t)(b * NKV + kv) * T_ * D_;

    *(int4*)&lds_seg[tid * 4] = *(const int4*)(seg + b * T_ + tid * 4);

    f16x8 vones;
#pragma unroll
    for (int j = 0; j < 8; ++j) vones[j] = (f16)1.0f;

    for (int sub = 0; sub < 2; ++sub) {
        const int tile = sub ? pair : (NTILE - 1 - pair);  // heavy tile first
        const int t0 = tile * BM;

        // ---- Q fragments (A-layout: m = ln, k = quad*8+j)
        const int qrow = t0 + wave * 16 + ln;
        const float* qptr = Qg + (((size_t)b * T_ + qrow) * NQ + h) * D_;
        f16x8 qfrag[4];
#pragma unroll
        for (int c = 0; c < 4; ++c) {
            const float* p = qptr + c * 32 + quad * 8;
            float4 f0 = *(const float4*)(p);
            float4 f1 = *(const float4*)(p + 4);
            f16x8 v;
            v[0] = (f16)f0.x; v[1] = (f16)f0.y; v[2] = (f16)f0.z; v[3] = (f16)f0.w;
            v[4] = (f16)f1.x; v[5] = (f16)f1.y; v[6] = (f16)f1.z; v[7] = (f16)f1.w;
            qfrag[c] = v;
        }

        __syncthreads();   // lds_seg visible (first sub) / prev sub's reads done

        int trow[4], segq[4];
#pragma unroll
        for (int r = 0; r < 4; ++r) {
            trow[r] = t0 + wave * 16 + quad * 4 + r;
            segq[r] = lds_seg[trow[r]];
        }
        const int seg_lo = lds_seg[t0];

        // first active KV block (sorted ids): ballot over dead 16-chunks
        unsigned long long bal = __ballot(lds_seg[lane * 16 + 15] < seg_lo);
        const int blk_start = __popcll(bal) >> 2;
        const int nblk = tile + 1;      // causal limit

        float  m_i[4];
        floatx4 o_acc[9];               // [8] = running row-sum (ones column)
#pragma unroll
        for (int r = 0; r < 4; ++r) m_i[r] = -1.0e30f;
#pragma unroll
        for (int dt = 0; dt < 9; ++dt) o_acc[dt] = floatx4{0.f, 0.f, 0.f, 0.f};

        // ---- prologue: DMA first block into buf 0 (drained by first body barrier)
        {
            const f16* kt = kbase + (size_t)blk_start * 8192 + glane;
            const f16* vt = vbase + (size_t)blk_start * 8192 + glane;
#pragma unroll
            for (int i = 0; i < 4; ++i) {
                dma16(kt + i * 512, kb0 + wbase + i * 512);
                dma16(vt + i * 512, vb0 + wbase + i * 512);
            }
        }

        int blk = blk_start;
        while (true) {
            FA_BODY(kb0, vb0, kb1, vb1, blk)
            if (++blk >= nblk) break;
            FA_BODY(kb1, vb1, kb0, vb0, blk)
            if (++blk >= nblk) break;
        }

        // ---- epilogue: normalize + store (fp32, C-layout scatter)
#pragma unroll
        for (int r = 0; r < 4; ++r) {
            const float inv = 1.0f / o_acc[8][r];
            float* optr = Og + (((size_t)b * T_ + trow[r]) * NQ + h) * D_ + ln;
#pragma unroll
            for (int dt = 0; dt < 8; ++dt)
                optr[dt * 16] = o_acc[dt][r] * inv;
        }
    }
}

extern "C" void kernel_launch(void* const* d_in, const int* in_sizes, int n_in,
                              void* d_out, int out_size, void* d_ws, size_t ws_size,
                              hipStream_t stream) {
    const float* Q   = (const float*)d_in[0];
    const float* K   = (const float*)d_in[1];
    const float* V   = (const float*)d_in[2];
    const int*   seg = (const int*)d_in[3];
    float* out = (float*)d_out;

    dim3 pgrid(NTILE, NKV, B_);
    prep_kernel<<<pgrid, 256, 0, stream>>>(K, V);

    dim3 grid(NTILE / 2, NQ, B_);
    fa_kernel<<<grid, 256, 0, stream>>>(Q, seg, out);
}